// Round 4
// baseline (557.847 us; speedup 1.0000x reference)
//
#include <hip/hip_runtime.h>
#include <hip/hip_bf16.h>
#include <math.h>

#define T_TOK 8192
#define D_DIM 2048
#define O_DIM 2048
#define E_NUM 8
#define BM 128
#define BN 128
#define BK 32

typedef __bf16 bf16_t;
typedef __bf16 bf16x8 __attribute__((ext_vector_type(8)));
typedef float fx4 __attribute__((ext_vector_type(4)));
typedef unsigned short us4 __attribute__((ext_vector_type(4)));

__device__ __forceinline__ unsigned short f2bf(float f) {
    unsigned int u = __builtin_bit_cast(unsigned int, f);
    u += 0x7FFFu + ((u >> 16) & 1u);           // round-to-nearest-even
    return (unsigned short)(u >> 16);
}

__device__ __forceinline__ void gll16(const void* g, void* l) {
    __builtin_amdgcn_global_load_lds(
        (const __attribute__((address_space(1))) void*)g,
        (__attribute__((address_space(3))) void*)l, 16, 0, 0);
}

// ---------------------------------------------------------------- convert W
__global__ __launch_bounds__(256) void convert_w_kernel(
    const float* __restrict__ w, bf16_t* __restrict__ wb, long n4) {
    long i = (long)blockIdx.x * blockDim.x + threadIdx.x;
    long stride = (long)gridDim.x * blockDim.x;
    const float4* w4 = (const float4*)w;
    us4* o4 = (us4*)wb;
    for (; i < n4; i += stride) {
        float4 v = w4[i];
        us4 o = { f2bf(v.x), f2bf(v.y), f2bf(v.z), f2bf(v.w) };
        o4[i] = o;
    }
}

// ---------------------------------------------------------------- gating
// one wave per token: fp32 logits, top-2, softmax, push to expert lists,
// fused x -> bf16 conversion.
__global__ __launch_bounds__(256) void gate_kernel(
    const float* __restrict__ x, const float* __restrict__ gw,
    bf16_t* __restrict__ xb, int* __restrict__ cnt,
    int* __restrict__ tok_list, float* __restrict__ wgt_list) {
    int wid = threadIdx.x >> 6, lane = threadIdx.x & 63;
    int t = blockIdx.x * 4 + wid;

    const float4* xrow = (const float4*)(x + (size_t)t * D_DIM);
    float4 xv[8];
#pragma unroll
    for (int i = 0; i < 8; ++i) xv[i] = xrow[i * 64 + lane];

    float acc[E_NUM];
#pragma unroll
    for (int e = 0; e < E_NUM; ++e) {
        const float4* gr = (const float4*)(gw + (size_t)e * D_DIM);
        float s = 0.f;
#pragma unroll
        for (int i = 0; i < 8; ++i) {
            float4 g = gr[i * 64 + lane];
            s += xv[i].x * g.x + xv[i].y * g.y + xv[i].z * g.z + xv[i].w * g.w;
        }
        acc[e] = s;
    }
#pragma unroll
    for (int m = 1; m < 64; m <<= 1) {
#pragma unroll
        for (int e = 0; e < E_NUM; ++e) acc[e] += __shfl_xor(acc[e], m, 64);
    }

    // fused bf16 conversion of x
    us4* xbr = (us4*)(xb + (size_t)t * D_DIM);
#pragma unroll
    for (int i = 0; i < 8; ++i) {
        us4 o = { f2bf(xv[i].x), f2bf(xv[i].y), f2bf(xv[i].z), f2bf(xv[i].w) };
        xbr[i * 64 + lane] = o;
    }

    if (lane == 0) {
        int e0 = 0; float v0 = acc[0];
#pragma unroll
        for (int e = 1; e < E_NUM; ++e)
            if (acc[e] > v0) { v0 = acc[e]; e0 = e; }
        int e1 = -1; float v1 = -INFINITY;
#pragma unroll
        for (int e = 0; e < E_NUM; ++e)
            if (e != e0 && acc[e] > v1) { v1 = acc[e]; e1 = e; }
        float p1 = expf(v1 - v0);          // v0 is the max
        float denom = 1.f + p1;
        float w0 = 1.f / denom, w1 = p1 / denom;
        int s0 = atomicAdd(&cnt[e0], 1);
        tok_list[e0 * T_TOK + s0] = t; wgt_list[e0 * T_TOK + s0] = w0;
        int s1 = atomicAdd(&cnt[e1], 1);
        tok_list[e1 * T_TOK + s1] = t; wgt_list[e1 * T_TOK + s1] = w1;
    }
}

// ---------------------------------------------------------------- expert GEMM
// C[tok][n] += w_tok * ( x_bf[tok,:] . W_e[n,:] + b_e[n] )
// 128x128 tile, BK=32, 4 waves (2x2), mfma 16x16x32 bf16.
// Double-buffered 2-phase: STAGE(next); ds_read+MFMA on cur; __syncthreads().
// The barrier is __syncthreads() ON PURPOSE: s_barrier does NOT drain
// lgkmcnt, so a hand-rolled "vmcnt(0); s_barrier" lets a wave cross with
// ds_reads of `cur` still in flight while another wave's global_load_lds
// overwrites `cur` (rounds 2-3 race). __syncthreads' full
// vmcnt(0)+lgkmcnt(0) drain is the correct publish.
__global__ __launch_bounds__(256, 4) void expert_gemm(
    const bf16_t* __restrict__ xb, const bf16_t* __restrict__ wb,
    const float* __restrict__ eb, const int* __restrict__ cnt,
    const int* __restrict__ tok_list, const float* __restrict__ wgt_list,
    float* __restrict__ out) {
    int e = blockIdx.z;
    int count = cnt[e];
    int m0 = blockIdx.y * BM;
    if (m0 >= count) return;
    int n0 = blockIdx.x * BN;

    __shared__ alignas(16) bf16_t As[2][BM * BK];
    __shared__ alignas(16) bf16_t Bs[2][BN * BK];
    __shared__ int tok_s[BM];
    __shared__ float wgt_s[BM];

    int tid = threadIdx.x, wid = tid >> 6, lane = tid & 63;
    int wr = wid >> 1, wc = wid & 1;

    if (tid < BM) {
        int idx = m0 + tid;
        if (idx >= count) idx = count - 1;   // clamp; masked in epilogue
        tok_s[tid] = tok_list[e * T_TOK + idx];
        wgt_s[tid] = wgt_list[e * T_TOK + idx];
    }
    __syncthreads();

    // staging: each wave stages 16 rows (64 B each) of A-low/A-high/B-low/B-high.
    int srow0 = wid * 16 + (lane >> 2);
    int srow1 = 64 + srow0;
    int scol = (lane & 3) * 8;               // bf16 column within the 32-wide K-slab
    const bf16_t* gA0 = xb + (size_t)tok_s[srow0] * D_DIM + scol;
    const bf16_t* gA1 = xb + (size_t)tok_s[srow1] * D_DIM + scol;
    const bf16_t* wbase = wb + (size_t)e * O_DIM * D_DIM;
    const bf16_t* gB0 = wbase + (size_t)(n0 + srow0) * D_DIM + scol;
    const bf16_t* gB1 = wbase + (size_t)(n0 + srow1) * D_DIM + scol;
    int sO0 = (wid * 16) * BK;               // wave-uniform LDS offsets (elements)
    int sO1 = (64 + wid * 16) * BK;

#define STAGE(b, ko)                                                        \
    do {                                                                    \
        gll16(gA0 + (ko), &As[b][sO0]);                                     \
        gll16(gA1 + (ko), &As[b][sO1]);                                     \
        gll16(gB0 + (ko), &Bs[b][sO0]);                                     \
        gll16(gB1 + (ko), &Bs[b][sO1]);                                     \
    } while (0)

    fx4 acc[4][4];
#pragma unroll
    for (int m = 0; m < 4; ++m)
#pragma unroll
        for (int n = 0; n < 4; ++n) acc[m][n] = (fx4)0.f;

    int rrow = lane & 15, kh = lane >> 4;
    int aOff = (wr * 64 + rrow) * BK + kh * 8;   // element offset into As[b]
    int bOff = (wc * 64 + rrow) * BK + kh * 8;

    const int NT = D_DIM / BK;
    STAGE(0, 0);
    __syncthreads();                         // buffer 0 ready for all waves

    for (int kt = 0; kt < NT; ++kt) {
        int cur = kt & 1;
        if (kt + 1 < NT) STAGE(cur ^ 1, (kt + 1) * BK);  // prefetch next tile

        bf16x8 af[4], bfr[4];
#pragma unroll
        for (int m = 0; m < 4; ++m)
            af[m] = *(const bf16x8*)(&As[cur][aOff + m * 16 * BK]);
#pragma unroll
        for (int n = 0; n < 4; ++n)
            bfr[n] = *(const bf16x8*)(&Bs[cur][bOff + n * 16 * BK]);
#pragma unroll
        for (int m = 0; m < 4; ++m)
#pragma unroll
            for (int n = 0; n < 4; ++n)
                acc[m][n] = __builtin_amdgcn_mfma_f32_16x16x32_bf16(
                    af[m], bfr[n], acc[m][n], 0, 0, 0);

        // full drain (vmcnt+lgkmcnt) + barrier: prefetch published, all
        // reads of `cur` complete before next iteration overwrites it.
        __syncthreads();
    }
#undef STAGE

    // epilogue: C/D layout col=lane&15, row=(lane>>4)*4+j
    const float* ebias = eb + (size_t)e * O_DIM;
#pragma unroll
    for (int n = 0; n < 4; ++n) {
        int gcol = n0 + wc * 64 + n * 16 + rrow;
        float bias = ebias[gcol];
#pragma unroll
        for (int m = 0; m < 4; ++m) {
            int rbase = wr * 64 + m * 16 + kh * 4;
#pragma unroll
            for (int j = 0; j < 4; ++j) {
                int r = rbase + j;
                if (m0 + r < count) {
                    float v = wgt_s[r] * (acc[m][n][j] + bias);
                    unsafeAtomicAdd(out + (size_t)tok_s[r] * O_DIM + gcol, v);
                }
            }
        }
    }
}

// ---------------------------------------------------------------- launch
extern "C" void kernel_launch(void* const* d_in, const int* in_sizes, int n_in,
                              void* d_out, int out_size, void* d_ws, size_t ws_size,
                              hipStream_t stream) {
    const float* x        = (const float*)d_in[0];
    const float* gate_w   = (const float*)d_in[1];
    const float* expert_w = (const float*)d_in[2];
    const float* expert_b = (const float*)d_in[3];
    float* out = (float*)d_out;

    char* ws = (char*)d_ws;
    size_t off = 0;
    bf16_t* wb = (bf16_t*)(ws + off);      off += (size_t)E_NUM * O_DIM * D_DIM * 2;
    bf16_t* xb = (bf16_t*)(ws + off);      off += (size_t)T_TOK * D_DIM * 2;
    int*    tok_list = (int*)(ws + off);   off += (size_t)E_NUM * T_TOK * 4;
    float*  wgt_list = (float*)(ws + off); off += (size_t)E_NUM * T_TOK * 4;
    int*    cnt = (int*)(ws + off);        off += 64;

    hipMemsetAsync(cnt, 0, 64, stream);
    hipMemsetAsync(d_out, 0, (size_t)out_size * 4, stream);

    convert_w_kernel<<<4096, 256, 0, stream>>>(
        expert_w, wb, (long)E_NUM * O_DIM * D_DIM / 4);
    gate_kernel<<<T_TOK / 4, 256, 0, stream>>>(
        x, gate_w, xb, cnt, tok_list, wgt_list);
    dim3 grid(O_DIM / BN, T_TOK / BM, E_NUM);
    expert_gemm<<<grid, 256, 0, stream>>>(
        xb, wb, expert_b, cnt, tok_list, wgt_list, out);
}

// Round 5
// 547.815 us; speedup vs baseline: 1.0183x; 1.0183x over previous
//
#include <hip/hip_runtime.h>
#include <hip/hip_bf16.h>
#include <math.h>

#define T_TOK 8192
#define D_DIM 2048
#define O_DIM 2048
#define E_NUM 8
#define BM 128
#define BN 128
#define BK 32

typedef __bf16 bf16_t;
typedef __bf16 bf16x8 __attribute__((ext_vector_type(8)));
typedef float fx4 __attribute__((ext_vector_type(4)));
typedef unsigned short us4 __attribute__((ext_vector_type(4)));

__device__ __forceinline__ unsigned short f2bf(float f) {
    unsigned int u = __builtin_bit_cast(unsigned int, f);
    u += 0x7FFFu + ((u >> 16) & 1u);           // round-to-nearest-even
    return (unsigned short)(u >> 16);
}

__device__ __forceinline__ void gll16(const void* g, void* l) {
    __builtin_amdgcn_global_load_lds(
        (const __attribute__((address_space(1))) void*)g,
        (__attribute__((address_space(3))) void*)l, 16, 0, 0);
}

// ---------------------------------------------------------------- convert W
__global__ __launch_bounds__(256) void convert_w_kernel(
    const float* __restrict__ w, bf16_t* __restrict__ wb, long n4) {
    long i = (long)blockIdx.x * blockDim.x + threadIdx.x;
    long stride = (long)gridDim.x * blockDim.x;
    const float4* w4 = (const float4*)w;
    us4* o4 = (us4*)wb;
    for (; i < n4; i += stride) {
        float4 v = w4[i];
        us4 o = { f2bf(v.x), f2bf(v.y), f2bf(v.z), f2bf(v.w) };
        o4[i] = o;
    }
}

// ---------------------------------------------------------------- gating
__global__ __launch_bounds__(256) void gate_kernel(
    const float* __restrict__ x, const float* __restrict__ gw,
    bf16_t* __restrict__ xb, int* __restrict__ cnt,
    int* __restrict__ tok_list, float* __restrict__ wgt_list) {
    int wid = threadIdx.x >> 6, lane = threadIdx.x & 63;
    int t = blockIdx.x * 4 + wid;

    const float4* xrow = (const float4*)(x + (size_t)t * D_DIM);
    float4 xv[8];
#pragma unroll
    for (int i = 0; i < 8; ++i) xv[i] = xrow[i * 64 + lane];

    float acc[E_NUM];
#pragma unroll
    for (int e = 0; e < E_NUM; ++e) {
        const float4* gr = (const float4*)(gw + (size_t)e * D_DIM);
        float s = 0.f;
#pragma unroll
        for (int i = 0; i < 8; ++i) {
            float4 g = gr[i * 64 + lane];
            s += xv[i].x * g.x + xv[i].y * g.y + xv[i].z * g.z + xv[i].w * g.w;
        }
        acc[e] = s;
    }
#pragma unroll
    for (int m = 1; m < 64; m <<= 1) {
#pragma unroll
        for (int e = 0; e < E_NUM; ++e) acc[e] += __shfl_xor(acc[e], m, 64);
    }

    // fused bf16 conversion of x
    us4* xbr = (us4*)(xb + (size_t)t * D_DIM);
#pragma unroll
    for (int i = 0; i < 8; ++i) {
        us4 o = { f2bf(xv[i].x), f2bf(xv[i].y), f2bf(xv[i].z), f2bf(xv[i].w) };
        xbr[i * 64 + lane] = o;
    }

    if (lane == 0) {
        int e0 = 0; float v0 = acc[0];
#pragma unroll
        for (int e = 1; e < E_NUM; ++e)
            if (acc[e] > v0) { v0 = acc[e]; e0 = e; }
        int e1 = -1; float v1 = -INFINITY;
#pragma unroll
        for (int e = 0; e < E_NUM; ++e)
            if (e != e0 && acc[e] > v1) { v1 = acc[e]; e1 = e; }
        float p1 = expf(v1 - v0);          // v0 is the max
        float denom = 1.f + p1;
        float w0 = 1.f / denom, w1 = p1 / denom;
        int s0 = atomicAdd(&cnt[e0], 1);
        tok_list[e0 * T_TOK + s0] = t; wgt_list[e0 * T_TOK + s0] = w0;
        int s1 = atomicAdd(&cnt[e1], 1);
        tok_list[e1 * T_TOK + s1] = t; wgt_list[e1 * T_TOK + s1] = w1;
    }
}

// ---------------------------------------------------------------- expert GEMM
// Counted-vmcnt 2-phase (T3/T4 minimum form), race-audited:
//   loop: STAGE(next)                         // 4 global_load_lds in flight
//         s_waitcnt vmcnt(4)   [+clobber]     // cur's 4 loads (issued LAST
//                                             //  iteration) complete; next's stay
//         s_barrier            [+clobber]     // cur published to all waves
//         ds_read(cur) + MFMA
//         s_waitcnt lgkmcnt(0) [+clobber]     // my ds_reads PROCESSED before
//         s_barrier            [+clobber]     //  anyone overwrites cur
// Rounds 2-3 raced because lgkmcnt(0) was missing before the second barrier
// (s_barrier drains no counters — ISA §8). The empty "memory"-clobber asm
// after each barrier stops ds_reads / bias loads hoisting above it (and
// blocks LICM of epilogue global loads, which would desync the vmcnt count).
__global__ __launch_bounds__(256, 4) void expert_gemm(
    const bf16_t* __restrict__ xb, const bf16_t* __restrict__ wb,
    const float* __restrict__ eb, const int* __restrict__ cnt,
    const int* __restrict__ tok_list, const float* __restrict__ wgt_list,
    float* __restrict__ out) {
    int e = blockIdx.z;
    int count = cnt[e];
    int m0 = blockIdx.y * BM;
    if (m0 >= count) return;
    int n0 = blockIdx.x * BN;

    __shared__ alignas(16) bf16_t As[2][BM * BK];
    __shared__ alignas(16) bf16_t Bs[2][BN * BK];
    __shared__ int tok_s[BM];
    __shared__ float wgt_s[BM];

    int tid = threadIdx.x, wid = tid >> 6, lane = tid & 63;
    int wr = wid >> 1, wc = wid & 1;

    if (tid < BM) {
        int idx = m0 + tid;
        if (idx >= count) idx = count - 1;   // clamp; masked in epilogue
        tok_s[tid] = tok_list[e * T_TOK + idx];
        wgt_s[tid] = wgt_list[e * T_TOK + idx];
    }
    __syncthreads();

    // staging: each wave stages 16 rows (64 B each) of A-low/A-high/B-low/B-high.
    int srow0 = wid * 16 + (lane >> 2);
    int srow1 = 64 + srow0;
    int scol = (lane & 3) * 8;               // bf16 column within the 32-wide K-slab
    const bf16_t* gA0 = xb + (size_t)tok_s[srow0] * D_DIM + scol;
    const bf16_t* gA1 = xb + (size_t)tok_s[srow1] * D_DIM + scol;
    const bf16_t* wbase = wb + (size_t)e * O_DIM * D_DIM;
    const bf16_t* gB0 = wbase + (size_t)(n0 + srow0) * D_DIM + scol;
    const bf16_t* gB1 = wbase + (size_t)(n0 + srow1) * D_DIM + scol;
    int sO0 = (wid * 16) * BK;               // wave-uniform LDS offsets (elements)
    int sO1 = (64 + wid * 16) * BK;

#define STAGE(b, ko)                                                        \
    do {                                                                    \
        gll16(gA0 + (ko), &As[b][sO0]);                                     \
        gll16(gA1 + (ko), &As[b][sO1]);                                     \
        gll16(gB0 + (ko), &Bs[b][sO0]);                                     \
        gll16(gB1 + (ko), &Bs[b][sO1]);                                     \
    } while (0)

    fx4 acc[4][4];
#pragma unroll
    for (int m = 0; m < 4; ++m)
#pragma unroll
        for (int n = 0; n < 4; ++n) acc[m][n] = (fx4)0.f;

    int rrow = lane & 15, kh = lane >> 4;
    int aOff = (wr * 64 + rrow) * BK + kh * 8;   // element offset into As[b]
    int bOff = (wc * 64 + rrow) * BK + kh * 8;

    const int NT = D_DIM / BK;
    STAGE(0, 0);                             // outstanding: 4 (buf0)

    for (int kt = 0; kt < NT; ++kt) {
        int cur = kt & 1;
        if (kt + 1 < NT) {
            STAGE(cur ^ 1, (kt + 1) * BK);   // outstanding: cur 4 + next 4
            asm volatile("s_waitcnt vmcnt(4)" ::: "memory");   // cur complete
        } else {
            asm volatile("s_waitcnt vmcnt(0)" ::: "memory");
        }
        __builtin_amdgcn_s_barrier();        // cur visible to all waves
        asm volatile("" ::: "memory");       // nothing hoists above the barrier

        bf16x8 af[4], bfr[4];
#pragma unroll
        for (int m = 0; m < 4; ++m)
            af[m] = *(const bf16x8*)(&As[cur][aOff + m * 16 * BK]);
#pragma unroll
        for (int n = 0; n < 4; ++n)
            bfr[n] = *(const bf16x8*)(&Bs[cur][bOff + n * 16 * BK]);
#pragma unroll
        for (int m = 0; m < 4; ++m)
#pragma unroll
            for (int n = 0; n < 4; ++n)
                acc[m][n] = __builtin_amdgcn_mfma_f32_16x16x32_bf16(
                    af[m], bfr[n], acc[m][n], 0, 0, 0);

        asm volatile("s_waitcnt lgkmcnt(0)" ::: "memory");  // ds_reads done
        __builtin_amdgcn_s_barrier();        // now cur may be overwritten
        asm volatile("" ::: "memory");
    }
#undef STAGE

    // epilogue: C/D layout col=lane&15, row=(lane>>4)*4+j
    const float* ebias = eb + (size_t)e * O_DIM;
#pragma unroll
    for (int n = 0; n < 4; ++n) {
        int gcol = n0 + wc * 64 + n * 16 + rrow;
        float bias = ebias[gcol];
#pragma unroll
        for (int m = 0; m < 4; ++m) {
            int rbase = wr * 64 + m * 16 + kh * 4;
#pragma unroll
            for (int j = 0; j < 4; ++j) {
                int r = rbase + j;
                if (m0 + r < count) {
                    float v = wgt_s[r] * (acc[m][n][j] + bias);
                    unsafeAtomicAdd(out + (size_t)tok_s[r] * O_DIM + gcol, v);
                }
            }
        }
    }
}

// ---------------------------------------------------------------- launch
extern "C" void kernel_launch(void* const* d_in, const int* in_sizes, int n_in,
                              void* d_out, int out_size, void* d_ws, size_t ws_size,
                              hipStream_t stream) {
    const float* x        = (const float*)d_in[0];
    const float* gate_w   = (const float*)d_in[1];
    const float* expert_w = (const float*)d_in[2];
    const float* expert_b = (const float*)d_in[3];
    float* out = (float*)d_out;

    char* ws = (char*)d_ws;
    size_t off = 0;
    bf16_t* wb = (bf16_t*)(ws + off);      off += (size_t)E_NUM * O_DIM * D_DIM * 2;
    bf16_t* xb = (bf16_t*)(ws + off);      off += (size_t)T_TOK * D_DIM * 2;
    int*    tok_list = (int*)(ws + off);   off += (size_t)E_NUM * T_TOK * 4;
    float*  wgt_list = (float*)(ws + off); off += (size_t)E_NUM * T_TOK * 4;
    int*    cnt = (int*)(ws + off);        off += 64;

    hipMemsetAsync(cnt, 0, 64, stream);
    hipMemsetAsync(d_out, 0, (size_t)out_size * 4, stream);

    convert_w_kernel<<<4096, 256, 0, stream>>>(
        expert_w, wb, (long)E_NUM * O_DIM * D_DIM / 4);
    gate_kernel<<<T_TOK / 4, 256, 0, stream>>>(
        x, gate_w, xb, cnt, tok_list, wgt_list);
    dim3 grid(O_DIM / BN, T_TOK / BM, E_NUM);
    expert_gemm<<<grid, 256, 0, stream>>>(
        xb, wb, expert_b, cnt, tok_list, wgt_list, out);
}

// Round 6
// 489.132 us; speedup vs baseline: 1.1405x; 1.1200x over previous
//
#include <hip/hip_runtime.h>
#include <hip/hip_bf16.h>
#include <math.h>

#define T_TOK 8192
#define D_DIM 2048
#define O_DIM 2048
#define E_NUM 8
#define BM 128
#define BN 128
#define BK 32

typedef __bf16 bf16_t;
typedef __bf16 bf16x8 __attribute__((ext_vector_type(8)));
typedef float fx4 __attribute__((ext_vector_type(4)));
typedef unsigned short us4 __attribute__((ext_vector_type(4)));

__device__ __forceinline__ unsigned short f2bf(float f) {
    unsigned int u = __builtin_bit_cast(unsigned int, f);
    u += 0x7FFFu + ((u >> 16) & 1u);           // round-to-nearest-even
    return (unsigned short)(u >> 16);
}

__device__ __forceinline__ void gll16(const void* g, void* l) {
    __builtin_amdgcn_global_load_lds(
        (const __attribute__((address_space(1))) void*)g,
        (__attribute__((address_space(3))) void*)l, 16, 0, 0);
}

// ---------------------------------------------------------------- convert W
__global__ __launch_bounds__(256) void convert_w_kernel(
    const float* __restrict__ w, bf16_t* __restrict__ wb, long n4) {
    long i = (long)blockIdx.x * blockDim.x + threadIdx.x;
    long stride = (long)gridDim.x * blockDim.x;
    const float4* w4 = (const float4*)w;
    us4* o4 = (us4*)wb;
    for (; i < n4; i += stride) {
        float4 v = w4[i];
        us4 o = { f2bf(v.x), f2bf(v.y), f2bf(v.z), f2bf(v.w) };
        o4[i] = o;
    }
}

// ---------------------------------------------------------------- gating
// list entries encode (token<<1)|slot so each (token,slot) output row is
// produced by exactly one expert block -> plain stores, no atomics.
__global__ __launch_bounds__(256) void gate_kernel(
    const float* __restrict__ x, const float* __restrict__ gw,
    bf16_t* __restrict__ xb, int* __restrict__ cnt,
    int* __restrict__ tok_list, float* __restrict__ wgt_list) {
    int wid = threadIdx.x >> 6, lane = threadIdx.x & 63;
    int t = blockIdx.x * 4 + wid;

    const float4* xrow = (const float4*)(x + (size_t)t * D_DIM);
    float4 xv[8];
#pragma unroll
    for (int i = 0; i < 8; ++i) xv[i] = xrow[i * 64 + lane];

    float acc[E_NUM];
#pragma unroll
    for (int e = 0; e < E_NUM; ++e) {
        const float4* gr = (const float4*)(gw + (size_t)e * D_DIM);
        float s = 0.f;
#pragma unroll
        for (int i = 0; i < 8; ++i) {
            float4 g = gr[i * 64 + lane];
            s += xv[i].x * g.x + xv[i].y * g.y + xv[i].z * g.z + xv[i].w * g.w;
        }
        acc[e] = s;
    }
#pragma unroll
    for (int m = 1; m < 64; m <<= 1) {
#pragma unroll
        for (int e = 0; e < E_NUM; ++e) acc[e] += __shfl_xor(acc[e], m, 64);
    }

    // fused bf16 conversion of x
    us4* xbr = (us4*)(xb + (size_t)t * D_DIM);
#pragma unroll
    for (int i = 0; i < 8; ++i) {
        us4 o = { f2bf(xv[i].x), f2bf(xv[i].y), f2bf(xv[i].z), f2bf(xv[i].w) };
        xbr[i * 64 + lane] = o;
    }

    if (lane == 0) {
        int e0 = 0; float v0 = acc[0];
#pragma unroll
        for (int e = 1; e < E_NUM; ++e)
            if (acc[e] > v0) { v0 = acc[e]; e0 = e; }
        int e1 = -1; float v1 = -INFINITY;
#pragma unroll
        for (int e = 0; e < E_NUM; ++e)
            if (e != e0 && acc[e] > v1) { v1 = acc[e]; e1 = e; }
        float p1 = expf(v1 - v0);          // v0 is the max
        float denom = 1.f + p1;
        float w0 = 1.f / denom, w1 = p1 / denom;
        int s0 = atomicAdd(&cnt[e0], 1);
        tok_list[e0 * T_TOK + s0] = (t << 1);      // slot 0 -> out
        wgt_list[e0 * T_TOK + s0] = w0;
        int s1 = atomicAdd(&cnt[e1], 1);
        tok_list[e1 * T_TOK + s1] = (t << 1) | 1;  // slot 1 -> part
        wgt_list[e1 * T_TOK + s1] = w1;
    }
}

// ---------------------------------------------------------------- expert GEMM
// Counted-vmcnt 2-phase K-loop (round-5, proven correct). Epilogue writes
// w*(acc+bias) with PLAIN stores: slot0 rows to out, slot1 rows to part —
// every (token,slot,col) written exactly once, no atomics.
__global__ __launch_bounds__(256, 4) void expert_gemm(
    const bf16_t* __restrict__ xb, const bf16_t* __restrict__ wb,
    const float* __restrict__ eb, const int* __restrict__ cnt,
    const int* __restrict__ tok_list, const float* __restrict__ wgt_list,
    float* __restrict__ out, float* __restrict__ part) {
    int e = blockIdx.z;
    int count = cnt[e];
    int m0 = blockIdx.y * BM;
    if (m0 >= count) return;
    int n0 = blockIdx.x * BN;

    __shared__ alignas(16) bf16_t As[2][BM * BK];
    __shared__ alignas(16) bf16_t Bs[2][BN * BK];
    __shared__ int tok_s[BM];
    __shared__ float wgt_s[BM];

    int tid = threadIdx.x, wid = tid >> 6, lane = tid & 63;
    int wr = wid >> 1, wc = wid & 1;

    if (tid < BM) {
        int idx = m0 + tid;
        if (idx >= count) idx = count - 1;   // clamp; masked in epilogue
        tok_s[tid] = tok_list[e * T_TOK + idx];
        wgt_s[tid] = wgt_list[e * T_TOK + idx];
    }
    __syncthreads();

    // staging: each wave stages 16 rows (64 B each) of A-low/A-high/B-low/B-high.
    int srow0 = wid * 16 + (lane >> 2);
    int srow1 = 64 + srow0;
    int scol = (lane & 3) * 8;               // bf16 column within the 32-wide K-slab
    const bf16_t* gA0 = xb + (size_t)(tok_s[srow0] >> 1) * D_DIM + scol;
    const bf16_t* gA1 = xb + (size_t)(tok_s[srow1] >> 1) * D_DIM + scol;
    const bf16_t* wbase = wb + (size_t)e * O_DIM * D_DIM;
    const bf16_t* gB0 = wbase + (size_t)(n0 + srow0) * D_DIM + scol;
    const bf16_t* gB1 = wbase + (size_t)(n0 + srow1) * D_DIM + scol;
    int sO0 = (wid * 16) * BK;               // wave-uniform LDS offsets (elements)
    int sO1 = (64 + wid * 16) * BK;

#define STAGE(b, ko)                                                        \
    do {                                                                    \
        gll16(gA0 + (ko), &As[b][sO0]);                                     \
        gll16(gA1 + (ko), &As[b][sO1]);                                     \
        gll16(gB0 + (ko), &Bs[b][sO0]);                                     \
        gll16(gB1 + (ko), &Bs[b][sO1]);                                     \
    } while (0)

    fx4 acc[4][4];
#pragma unroll
    for (int m = 0; m < 4; ++m)
#pragma unroll
        for (int n = 0; n < 4; ++n) acc[m][n] = (fx4)0.f;

    int rrow = lane & 15, kh = lane >> 4;
    int aOff = (wr * 64 + rrow) * BK + kh * 8;   // element offset into As[b]
    int bOff = (wc * 64 + rrow) * BK + kh * 8;

    const int NT = D_DIM / BK;
    STAGE(0, 0);                             // outstanding: 4 (buf0)

    for (int kt = 0; kt < NT; ++kt) {
        int cur = kt & 1;
        if (kt + 1 < NT) {
            STAGE(cur ^ 1, (kt + 1) * BK);   // outstanding: cur 4 + next 4
            asm volatile("s_waitcnt vmcnt(4)" ::: "memory");   // cur complete
        } else {
            asm volatile("s_waitcnt vmcnt(0)" ::: "memory");
        }
        __builtin_amdgcn_s_barrier();        // cur visible to all waves
        asm volatile("" ::: "memory");       // nothing hoists above the barrier

        bf16x8 af[4], bfr[4];
#pragma unroll
        for (int m = 0; m < 4; ++m)
            af[m] = *(const bf16x8*)(&As[cur][aOff + m * 16 * BK]);
#pragma unroll
        for (int n = 0; n < 4; ++n)
            bfr[n] = *(const bf16x8*)(&Bs[cur][bOff + n * 16 * BK]);
#pragma unroll
        for (int m = 0; m < 4; ++m)
#pragma unroll
            for (int n = 0; n < 4; ++n)
                acc[m][n] = __builtin_amdgcn_mfma_f32_16x16x32_bf16(
                    af[m], bfr[n], acc[m][n], 0, 0, 0);

        asm volatile("s_waitcnt lgkmcnt(0)" ::: "memory");  // ds_reads done
        __builtin_amdgcn_s_barrier();        // now cur may be overwritten
        asm volatile("" ::: "memory");
    }
#undef STAGE

    // epilogue: C/D layout col=lane&15, row=(lane>>4)*4+j. Plain stores.
    const float* ebias = eb + (size_t)e * O_DIM;
#pragma unroll
    for (int n = 0; n < 4; ++n) {
        int gcol = n0 + wc * 64 + n * 16 + rrow;
        float bias = ebias[gcol];
#pragma unroll
        for (int m = 0; m < 4; ++m) {
            int rbase = wr * 64 + m * 16 + kh * 4;
#pragma unroll
            for (int j = 0; j < 4; ++j) {
                int r = rbase + j;
                if (m0 + r < count) {
                    int entry = tok_s[r];
                    float v = wgt_s[r] * (acc[m][n][j] + bias);
                    float* dst = (entry & 1) ? part : out;
                    dst[(size_t)(entry >> 1) * O_DIM + gcol] = v;
                }
            }
        }
    }
}

// ---------------------------------------------------------------- combine
__global__ __launch_bounds__(256) void combine_kernel(
    float* __restrict__ out, const float* __restrict__ part, long n4) {
    long i = (long)blockIdx.x * blockDim.x + threadIdx.x;
    long stride = (long)gridDim.x * blockDim.x;
    float4* o4 = (float4*)out;
    const float4* p4 = (const float4*)part;
    for (; i < n4; i += stride) {
        float4 a = o4[i], b = p4[i];
        a.x += b.x; a.y += b.y; a.z += b.z; a.w += b.w;
        o4[i] = a;
    }
}

// ---------------------------------------------------------------- launch
extern "C" void kernel_launch(void* const* d_in, const int* in_sizes, int n_in,
                              void* d_out, int out_size, void* d_ws, size_t ws_size,
                              hipStream_t stream) {
    const float* x        = (const float*)d_in[0];
    const float* gate_w   = (const float*)d_in[1];
    const float* expert_w = (const float*)d_in[2];
    const float* expert_b = (const float*)d_in[3];
    float* out = (float*)d_out;

    char* ws = (char*)d_ws;
    size_t off = 0;
    bf16_t* wb = (bf16_t*)(ws + off);      off += (size_t)E_NUM * O_DIM * D_DIM * 2;
    bf16_t* xb = (bf16_t*)(ws + off);      off += (size_t)T_TOK * D_DIM * 2;
    float*  part = (float*)(ws + off);     off += (size_t)T_TOK * O_DIM * 4;
    int*    tok_list = (int*)(ws + off);   off += (size_t)E_NUM * T_TOK * 4;
    float*  wgt_list = (float*)(ws + off); off += (size_t)E_NUM * T_TOK * 4;
    int*    cnt = (int*)(ws + off);        off += 64;

    hipMemsetAsync(cnt, 0, 64, stream);

    convert_w_kernel<<<4096, 256, 0, stream>>>(
        expert_w, wb, (long)E_NUM * O_DIM * D_DIM / 4);
    gate_kernel<<<T_TOK / 4, 256, 0, stream>>>(
        x, gate_w, xb, cnt, tok_list, wgt_list);
    dim3 grid(O_DIM / BN, T_TOK / BM, E_NUM);
    expert_gemm<<<grid, 256, 0, stream>>>(
        xb, wb, expert_b, cnt, tok_list, wgt_list, out, part);
    combine_kernel<<<2048, 256, 0, stream>>>(
        out, part, (long)T_TOK * O_DIM / 4);
}